// Round 4
// baseline (424.711 us; speedup 1.0000x reference)
//
#include <hip/hip_runtime.h>

// ===== DIAGNOSTIC ROUND =====
// Identical to R3 kernel except phase 3 repeats the real-coordinate res2
// gather 64x (63 keep-alive passes + 1 real pass). Offsets are laundered
// through inline asm each iteration so the compiler cannot CSE/hoist the
// loads. Purpose: measure warm-gather cost via dur_us slope:
//   dur_us(R4) - dur_us(R3) = 63 * T_gather_warm.
// Output remains exactly correct (the final pass computes the real result).

__device__ __forceinline__ void bilin_setup(float px, float py, int H, int W,
                                            int idx[4], float cw[4]) {
    // Replicates the reference op order exactly.
    float gx = 2.0f * px - 1.0f;
    float gy = 2.0f * py - 1.0f;
    float x = ((gx + 1.0f) * (float)W - 1.0f) * 0.5f;
    float y = ((gy + 1.0f) * (float)H - 1.0f) * 0.5f;
    float x0 = floorf(x), y0 = floorf(y);
    float wx1 = x - x0, wy1 = y - y0;
    float wxs[2] = {1.0f - wx1, wx1};
    float wys[2] = {1.0f - wy1, wy1};
    float xs[2] = {x0, x0 + 1.0f};
    float ys[2] = {y0, y0 + 1.0f};
#pragma unroll
    for (int dy = 0; dy < 2; ++dy) {
#pragma unroll
        for (int dx = 0; dx < 2; ++dx) {
            float xf = xs[dx], yf = ys[dy];
            bool valid = (xf >= 0.0f) && (xf <= (float)(W - 1)) &&
                         (yf >= 0.0f) && (yf <= (float)(H - 1));
            float xc = fminf(fmaxf(xf, 0.0f), (float)(W - 1));
            float yc = fminf(fmaxf(yf, 0.0f), (float)(H - 1));
            int xi = (int)xc, yi = (int)yc;
            idx[dy * 2 + dx] = yi * W + xi;
            cw[dy * 2 + dx] = valid ? (wys[dy] * wxs[dx]) : 0.0f;
        }
    }
}

__global__ __launch_bounds__(1024, 8) void k_fused(
    const float* __restrict__ outm,   // [8,2,64,64]
    const float* __restrict__ res2,   // [8,512,256,256]
    const float* __restrict__ w,      // [2,514]
    const float* __restrict__ bias,   // [2]
    const float* __restrict__ og,     // [8,192,2]
    const float* __restrict__ cov,    // [8,16,2]
    float* __restrict__ rend,         // [8,2,64]
    float* __restrict__ points) {     // [8,64,2]
    const int b = blockIdx.x >> 6;
    const int n = blockIdx.x & 63;
    const int t = threadIdx.x;

    __shared__ float u[192];
    __shared__ float sp[2];

    if (n < 48) {
        // Phase 1: uncertainty for all 192 candidates of batch b.
        if (t < 192) {
            float2 p = ((const float2*)og)[b * 192 + t];
            int idx[4];
            float cw[4];
            bilin_setup(p.x, p.y, 64, 64, idx, cw);
            const float* c0 = outm + (size_t)b * 2 * 4096;
            const float* c1 = c0 + 4096;
            float s0 = 0.0f, s1 = 0.0f;
#pragma unroll
            for (int k = 0; k < 4; ++k) {
                float a = c0[idx[k]];
                float d = c1[idx[k]];
                s0 += fmaxf(a, d) * cw[k];  // mask_sorted ch0 = per-pixel max
                s1 += fminf(a, d) * cw[k];  // mask_sorted ch1 = per-pixel min
            }
            u[t] = s1 - s0;  // uncertainty = -(max_samp - min_samp)
        }
        __syncthreads();
        // Phase 2: which candidate has rank n? (lax.top_k order)
        if (t < 192) {
            float ui = u[t];
            int rank = 0;
            for (int j = 0; j < 192; ++j) {
                float uj = u[j];
                rank += (uj > ui || (uj == ui && j < t)) ? 1 : 0;
            }
            if (rank == n) {
                float2 p = ((const float2*)og)[b * 192 + t];
                sp[0] = p.x;
                sp[1] = p.y;
            }
        }
        __syncthreads();
    } else {
        if (t == 0) {
            float2 p = ((const float2*)cov)[b * 16 + (n - 48)];
            sp[0] = p.x;
            sp[1] = p.y;
        }
        __syncthreads();
    }

    const float px = sp[0], py = sp[1];
    if (t == 1) {
        points[b * 128 + n * 2 + 0] = px;
        points[b * 128 + n * 2 + 1] = py;
    }

    // Coarse sample on thread 0, issued concurrently with the gather below.
    float coarse0 = 0.0f, coarse1 = 0.0f;
    if (t == 0) {
        int idc[4];
        float cwc[4];
        bilin_setup(px, py, 64, 64, idc, cwc);
        const float* c0p = outm + (size_t)b * 2 * 4096;
        const float* c1p = c0p + 4096;
        coarse0 = c0p[idc[0]] * cwc[0] + c0p[idc[1]] * cwc[1] +
                  c0p[idc[2]] * cwc[2] + c0p[idc[3]] * cwc[3];
        coarse1 = c1p[idc[0]] * cwc[0] + c1p[idc[1]] * cwc[1] +
                  c1p[idc[2]] * cwc[2] + c1p[idc[3]] * cwc[3];
    }

    // Phase 3: gather. channel c = t&511, row half = t>>9.
    int idx[4];
    float cw[4];
    bilin_setup(px, py, 256, 256, idx, cw);
    const int c = t & 511;
    const int half = t >> 9;
    const float* base = res2 + ((size_t)b * 512 + c) * 65536;
    const int i0 = idx[2 * half];
    const int i1 = idx[2 * half + 1];
    const float cw0 = cw[2 * half];
    const float cw1 = cw[2 * half + 1];

    // --- DIAG: 63 keep-alive repeats of the exact same gather ---
    float accd = 0.0f;
#pragma unroll 4
    for (int r = 0; r < 63; ++r) {
        int o0 = i0, o1 = i1;
        asm volatile("" : "+v"(o0), "+v"(o1));  // launder: defeat CSE/hoist
        accd += base[o0] * cw0 + base[o1] * cw1;
    }
    asm volatile("" :: "v"(accd));  // keep dummy result live

    // --- real pass ---
    float f = base[i0] * cw0 + base[i1] * cw1;
    float acc0 = w[2 + c] * f;        // w[0][2+c]
    float acc1 = w[516 + c] * f;      // w[1][2+c]

    // wave (64-lane) shuffle reduce, then 16 partials via LDS
#pragma unroll
    for (int off = 32; off > 0; off >>= 1) {
        acc0 += __shfl_down(acc0, off, 64);
        acc1 += __shfl_down(acc1, off, 64);
    }
    __shared__ float r0s[16], r1s[16];
    const int wid = t >> 6, lane = t & 63;
    if (lane == 0) {
        r0s[wid] = acc0;
        r1s[wid] = acc1;
    }
    __syncthreads();
    if (t == 0) {
        float a0 = 0.0f, a1 = 0.0f;
#pragma unroll
        for (int i = 0; i < 16; ++i) {
            a0 += r0s[i];
            a1 += r1s[i];
        }
        rend[((size_t)b * 2 + 0) * 64 + n] = w[0] * coarse0 + w[1] * coarse1 + a0 + bias[0];
        rend[((size_t)b * 2 + 1) * 64 + n] = w[514] * coarse0 + w[515] * coarse1 + a1 + bias[1];
    }
}

extern "C" void kernel_launch(void* const* d_in, const int* in_sizes, int n_in,
                              void* d_out, int out_size, void* d_ws, size_t ws_size,
                              hipStream_t stream) {
    // inputs: 0:x (unused), 1:res2, 2:out, 3:over_generation, 4:coverage, 5:w, 6:b
    const float* res2 = (const float*)d_in[1];
    const float* outm = (const float*)d_in[2];
    const float* og   = (const float*)d_in[3];
    const float* cov  = (const float*)d_in[4];
    const float* w    = (const float*)d_in[5];
    const float* bias = (const float*)d_in[6];

    float* rend = (float*)d_out;    // [8,2,64] = 1024 floats
    float* points = rend + 1024;    // [8,64,2] = 1024 floats

    k_fused<<<512, 1024, 0, stream>>>(outm, res2, w, bias, og, cov, rend, points);
}

// Round 5
// 21.369 us; speedup vs baseline: 19.8749x; 19.8749x over previous
//
#include <hip/hip_runtime.h>

// PointRend-style head, fully fused into ONE kernel launch.
//   points = top-48-uncertainty(over_generation) ++ coverage   -> [8,64,2]
//   rend   = w @ concat(bilinear(out,points), bilinear(res2,points)) + b -> [8,2,64]
// Output layout: d_out = [rend (1024 floats)][points (1024 floats)]
// Input x (d_in[0]) is shape-only in the reference; never read.
//
// R4 diag: warm gather pass = 6.4 us, throughput-limited by scattered-line
// service (not occupancy). R5: cut per-thread request count 2.0 -> 1.25 via
// one aligned dwordx4 per row (16B block containing x0; x0%4==3 needs one
// extra dword). v0/v1 extracted with cndmask chains (no runtime vector
// indexing -> no scratch).

__device__ __forceinline__ void bilin_setup(float px, float py, int H, int W,
                                            int idx[4], float cw[4]) {
    // Replicates the reference op order exactly.
    float gx = 2.0f * px - 1.0f;
    float gy = 2.0f * py - 1.0f;
    float x = ((gx + 1.0f) * (float)W - 1.0f) * 0.5f;
    float y = ((gy + 1.0f) * (float)H - 1.0f) * 0.5f;
    float x0 = floorf(x), y0 = floorf(y);
    float wx1 = x - x0, wy1 = y - y0;
    float wxs[2] = {1.0f - wx1, wx1};
    float wys[2] = {1.0f - wy1, wy1};
    float xs[2] = {x0, x0 + 1.0f};
    float ys[2] = {y0, y0 + 1.0f};
#pragma unroll
    for (int dy = 0; dy < 2; ++dy) {
#pragma unroll
        for (int dx = 0; dx < 2; ++dx) {
            float xf = xs[dx], yf = ys[dy];
            bool valid = (xf >= 0.0f) && (xf <= (float)(W - 1)) &&
                         (yf >= 0.0f) && (yf <= (float)(H - 1));
            float xc = fminf(fmaxf(xf, 0.0f), (float)(W - 1));
            float yc = fminf(fmaxf(yf, 0.0f), (float)(H - 1));
            int xi = (int)xc, yi = (int)yc;
            idx[dy * 2 + dx] = yi * W + xi;
            cw[dy * 2 + dx] = valid ? (wys[dy] * wxs[dx]) : 0.0f;
        }
    }
}

__global__ __launch_bounds__(1024, 8) void k_fused(
    const float* __restrict__ outm,   // [8,2,64,64]
    const float* __restrict__ res2,   // [8,512,256,256]
    const float* __restrict__ w,      // [2,514]
    const float* __restrict__ bias,   // [2]
    const float* __restrict__ og,     // [8,192,2]
    const float* __restrict__ cov,    // [8,16,2]
    float* __restrict__ rend,         // [8,2,64]
    float* __restrict__ points) {     // [8,64,2]
    const int b = blockIdx.x >> 6;
    const int n = blockIdx.x & 63;
    const int t = threadIdx.x;

    __shared__ float u[192];
    __shared__ float sp[2];

    if (n < 48) {
        // Phase 1: uncertainty for all 192 candidates of batch b.
        if (t < 192) {
            float2 p = ((const float2*)og)[b * 192 + t];
            int idx[4];
            float cw[4];
            bilin_setup(p.x, p.y, 64, 64, idx, cw);
            const float* c0 = outm + (size_t)b * 2 * 4096;
            const float* c1 = c0 + 4096;
            float s0 = 0.0f, s1 = 0.0f;
#pragma unroll
            for (int k = 0; k < 4; ++k) {
                float a = c0[idx[k]];
                float d = c1[idx[k]];
                s0 += fmaxf(a, d) * cw[k];  // mask_sorted ch0 = per-pixel max
                s1 += fminf(a, d) * cw[k];  // mask_sorted ch1 = per-pixel min
            }
            u[t] = s1 - s0;  // uncertainty = -(max_samp - min_samp)
        }
        __syncthreads();
        // Phase 2: which candidate has rank n? (lax.top_k order: descending
        // value, ties -> lower index first; ranks are unique)
        if (t < 192) {
            float ui = u[t];
            int rank = 0;
            for (int j = 0; j < 192; ++j) {
                float uj = u[j];
                rank += (uj > ui || (uj == ui && j < t)) ? 1 : 0;
            }
            if (rank == n) {
                float2 p = ((const float2*)og)[b * 192 + t];
                sp[0] = p.x;
                sp[1] = p.y;
            }
        }
        __syncthreads();
    } else {
        if (t == 0) {
            float2 p = ((const float2*)cov)[b * 16 + (n - 48)];
            sp[0] = p.x;
            sp[1] = p.y;
        }
        __syncthreads();
    }

    const float px = sp[0], py = sp[1];
    if (t == 1) {
        points[b * 128 + n * 2 + 0] = px;
        points[b * 128 + n * 2 + 1] = py;
    }

    // Coarse sample on thread 0, issued concurrently with the gather below.
    float coarse0 = 0.0f, coarse1 = 0.0f;
    if (t == 0) {
        int idc[4];
        float cwc[4];
        bilin_setup(px, py, 64, 64, idc, cwc);
        const float* c0p = outm + (size_t)b * 2 * 4096;
        const float* c1p = c0p + 4096;
        coarse0 = c0p[idc[0]] * cwc[0] + c0p[idc[1]] * cwc[1] +
                  c0p[idc[2]] * cwc[2] + c0p[idc[3]] * cwc[3];
        coarse1 = c1p[idc[0]] * cwc[0] + c1p[idc[1]] * cwc[1] +
                  c1p[idc[2]] * cwc[2] + c1p[idc[3]] * cwc[3];
    }

    // Phase 3: res2 gather. channel c = t&511, row half = t>>9 (y0 or y0+1).
    // One aligned dwordx4 covers x0..x0+1 unless x0%4==3 (then +1 dword).
    {
        const int c = t & 511;
        const int half = t >> 9;
        float gx = 2.0f * px - 1.0f;
        float gy = 2.0f * py - 1.0f;
        float x = ((gx + 1.0f) * 256.0f - 1.0f) * 0.5f;
        float y = ((gy + 1.0f) * 256.0f - 1.0f) * 0.5f;
        float x0f = floorf(x), y0f = floorf(y);
        float wx1 = x - x0f, wy1 = y - y0f;

        float yf = y0f + (float)half;
        float wy = half ? wy1 : (1.0f - wy1);
        bool vy = (yf >= 0.0f) && (yf <= 255.0f);
        int yi = (int)fminf(fmaxf(yf, 0.0f), 255.0f);

        float x1f = x0f + 1.0f;
        bool vx0 = (x0f >= 0.0f) && (x0f <= 255.0f);
        bool vx1 = (x1f >= 0.0f) && (x1f <= 255.0f);
        // reference weight order: (wy * wx), zeroed if invalid
        float cw0 = (vy && vx0) ? (wy * (1.0f - wx1)) : 0.0f;
        float cw1 = (vy && vx1) ? (wy * wx1) : 0.0f;
        int xc0 = (int)fminf(fmaxf(x0f, 0.0f), 255.0f);
        int xc1 = (int)fminf(fmaxf(x1f, 0.0f), 255.0f);

        const float* rowp = res2 + ((size_t)b * 512 + c) * 65536 + yi * 256;
        const int r = xc0 & 3;
        const float4 q = *(const float4*)(rowp + (xc0 - r));
        float v0 = q.x;
        v0 = (r == 1) ? q.y : v0;
        v0 = (r == 2) ? q.z : v0;
        v0 = (r == 3) ? q.w : v0;
        float v1;
        if (r == 3 && xc1 != xc0) {
            v1 = rowp[xc1];  // rare: next 16B block
        } else {
            float tn = (r == 0) ? q.y : ((r == 1) ? q.z : q.w);
            v1 = (xc1 == xc0) ? v0 : tn;
        }
        float f = v0 * cw0 + v1 * cw1;
        float acc0 = w[2 + c] * f;        // w[0][2+c]
        float acc1 = w[516 + c] * f;      // w[1][2+c]

        // wave (64-lane) shuffle reduce, then 16 partials via LDS
#pragma unroll
        for (int off = 32; off > 0; off >>= 1) {
            acc0 += __shfl_down(acc0, off, 64);
            acc1 += __shfl_down(acc1, off, 64);
        }
        __shared__ float r0s[16], r1s[16];
        const int wid = t >> 6, lane = t & 63;
        if (lane == 0) {
            r0s[wid] = acc0;
            r1s[wid] = acc1;
        }
        __syncthreads();
        if (t == 0) {
            float a0 = 0.0f, a1 = 0.0f;
#pragma unroll
            for (int i = 0; i < 16; ++i) {
                a0 += r0s[i];
                a1 += r1s[i];
            }
            rend[((size_t)b * 2 + 0) * 64 + n] = w[0] * coarse0 + w[1] * coarse1 + a0 + bias[0];
            rend[((size_t)b * 2 + 1) * 64 + n] = w[514] * coarse0 + w[515] * coarse1 + a1 + bias[1];
        }
    }
}

extern "C" void kernel_launch(void* const* d_in, const int* in_sizes, int n_in,
                              void* d_out, int out_size, void* d_ws, size_t ws_size,
                              hipStream_t stream) {
    // inputs: 0:x (unused), 1:res2, 2:out, 3:over_generation, 4:coverage, 5:w, 6:b
    const float* res2 = (const float*)d_in[1];
    const float* outm = (const float*)d_in[2];
    const float* og   = (const float*)d_in[3];
    const float* cov  = (const float*)d_in[4];
    const float* w    = (const float*)d_in[5];
    const float* bias = (const float*)d_in[6];

    float* rend = (float*)d_out;    // [8,2,64] = 1024 floats
    float* points = rend + 1024;    // [8,64,2] = 1024 floats

    k_fused<<<512, 1024, 0, stream>>>(outm, res2, w, bias, og, cov, rend, points);
}